// Round 13
// baseline (283.855 us; speedup 1.0000x reference)
//
#include <hip/hip_runtime.h>
#include <hip/hip_cooperative_groups.h>
#include <cstdint>
#include <cstddef>

namespace cg = cooperative_groups;

// ---------------- problem constants ----------------
#define B_ 2
#define N_ 19248
#define NCLSP1_ 81
#define NCLS_ 80
#define MAXK_ 100
#define MAXOUT_ 300
#define PH_ 138
#define PW_ 138
#define PHW_ (PH_*PW_)      // 19044
#define MD_ 32
#define NBC_ (B_*NCLS_)     // 160
#define CAP_ 768            // per-(b,c) pool capacity (observed max M ~190)
#define SCORE_THR_ 0.3f
#define IOU_THR_ 0.5f
#define KCHUNK 75           // 300/4
#define GRID_ 256           // 1 block/CU -> cooperative co-residency guaranteed
#define NTILE 608           // 76 x 4 x 2 mask tiles (grid-strided in P4)

// output layout (flat float32 elements in d_out)
#define OUT_BOXES 0
#define OUT_CLS   2400
#define OUT_SCR   3000
#define OUT_MASKS 3600
#define OUT_NDET  11430000
#define OUT_HEAD  3600                     // boxes+cls+scores elements

// workspace layout (element offsets)
#define OFF_CURSORS 0                      // 160*16 ints (one 64B line per class)
#define OFF_BFLAG   2560                   // 2 ints
#define POOLSZ      (NBC_*CAP_)            // 122880
#define OFF_PS      2576
#define OFF_PY1     (OFF_PS  + POOLSZ)
#define OFF_PX1     (OFF_PY1 + POOLSZ)
#define OFF_PY2     (OFF_PX1 + POOLSZ)
#define OFF_PX2     (OFF_PY2 + POOLSZ)
#define OFF_PA      (OFF_PX2 + POOLSZ)
#define OFF_PIDX    (OFF_PA  + POOLSZ)
#define OFF_NSCORE  (OFF_PIDX + POOLSZ)    // 160*100
#define OFF_NANCH   (OFF_NSCORE + NBC_*MAXK_)
#define OFF_SELC    (OFF_NANCH + NBC_*MAXK_)

// ---------------- wave-wide reduce via DPP (no DS ops) ----------------
__device__ __forceinline__ float wave_max_f32(float x) {
    int v = __float_as_int(x);
    int t;
    #define DPPMAX(ctrl, rm, bm) \
        t = __builtin_amdgcn_update_dpp(v, v, ctrl, rm, bm, false); \
        v = __float_as_int(fmaxf(__int_as_float(v), __int_as_float(t)));
    DPPMAX(0x111, 0xF, 0xF)   // row_shr:1
    DPPMAX(0x112, 0xF, 0xF)   // row_shr:2
    DPPMAX(0x114, 0xF, 0xE)   // row_shr:4
    DPPMAX(0x118, 0xF, 0xC)   // row_shr:8
    DPPMAX(0x142, 0xA, 0xF)   // row_bcast:15
    DPPMAX(0x143, 0xC, 0xF)   // row_bcast:31 ; lane 63 holds wave max
    #undef DPPMAX
    return __int_as_float(__builtin_amdgcn_readlane(v, 63));
}

__device__ __forceinline__ float wave_sum_f32(float x) {
    int v = __float_as_int(x);
    int t;
    #define DPPSUM(ctrl, rm, bm) \
        t = __builtin_amdgcn_update_dpp(v, v, ctrl, rm, bm, false); \
        v = __float_as_int(__int_as_float(v) + __int_as_float(t));
    DPPSUM(0x111, 0xF, 0xF)
    DPPSUM(0x112, 0xF, 0xF)
    DPPSUM(0x114, 0xF, 0xE)
    DPPSUM(0x118, 0xF, 0xC)
    DPPSUM(0x142, 0xA, 0xF)
    DPPSUM(0x143, 0xC, 0xF)
    #undef DPPSUM
    return __int_as_float(__builtin_amdgcn_readlane(v, 63));
}

__device__ __forceinline__ float readlane_f(float v, int l) {
    return __int_as_float(__builtin_amdgcn_readlane(__float_as_int(v), l));
}

// ---------------- per-(b,c) soft-NMS — r11 self-suppress-by-weight step ----------------
template<int J>
__device__ __forceinline__ void nms_reg(int bc, int M, int lane,
        const float* __restrict__ ps, const float* __restrict__ py1,
        const float* __restrict__ px1, const float* __restrict__ py2,
        const float* __restrict__ px2, const float* __restrict__ pa,
        const int* __restrict__ pidx,
        float* __restrict__ nscore, int* __restrict__ nanchor) {
    int base = bc * CAP_;
    float s[J], y1[J], x1[J], y2[J], x2[J], a[J];
    int pid[J];
    #pragma unroll
    for (int j = 0; j < J; j++) {
        int m = lane + 64 * j;
        bool in = (m < M);
        s[j]  = in ? ps[base + m]  : 0.f;    // scores >= 0; padding 0 never selected
        y1[j] = in ? py1[base + m] : 0.f;
        x1[j] = in ? px1[base + m] : 0.f;
        y2[j] = in ? py2[base + m] : 0.f;
        x2[j] = in ? px2[base + m] : 0.f;
        a[j]  = in ? pa[base + m]  : 0.f;    // zero box: inter=0 -> iou 0 -> w 1
        pid[j] = in ? pidx[base + m] : 0;
    }
    float lm = s[0];
    #pragma unroll
    for (int j = 1; j < J; j++) lm = fmaxf(lm, s[j]);
    for (int k = 0; k < MAXK_; k++) {
        float maxv = wave_max_f32(lm);
        if (!(maxv > SCORE_THR_)) break;      // remaining outputs stay 0 (= invalid)
        unsigned long long bb[J];
        #pragma unroll
        for (int j = 0; j < J; j++) bb[j] = __ballot(s[j] == maxv);
        int bsel = 0;
        #pragma unroll
        for (int j = J - 1; j >= 0; j--) if (bb[j]) bsel = 64 * j + (__ffsll((long long)bb[j]) - 1);
        int lsel = bsel & 63;
        float ty1, tx1, ty2, tx2; int tpd;
        if (J == 1) {
            ty1 = y1[0]; tx1 = x1[0]; ty2 = y2[0]; tx2 = x2[0]; tpd = pid[0];
        } else {
            int jsel = bsel >> 6;
            ty1 = y1[0]; tx1 = x1[0]; ty2 = y2[0]; tx2 = x2[0]; tpd = pid[0];
            #pragma unroll
            for (int j = 1; j < J; j++) {
                if (j == jsel) { ty1 = y1[j]; tx1 = x1[j]; ty2 = y2[j]; tx2 = x2[j]; tpd = pid[j]; }
            }
        }
        float by1 = readlane_f(ty1, lsel);
        float bx1 = readlane_f(tx1, lsel);
        float by2 = readlane_f(ty2, lsel);
        float bx2 = readlane_f(tx2, lsel);
        int   bpd = __builtin_amdgcn_readlane(tpd, lsel);
        float ba  = (by2 - by1) * (bx2 - bx1);   // bitwise == stored pa (same expression)
        if (lane == 0) {
            nscore[bc * MAXK_ + k] = maxv;
            nanchor[bc * MAXK_ + k] = bpd;
        }
        lm = 0.f;
        #pragma unroll
        for (int j = 0; j < J; j++) {
            float iy1 = fmaxf(y1[j], by1), ix1 = fmaxf(x1[j], bx1);
            float iy2 = fminf(y2[j], by2), ix2 = fminf(x2[j], bx2);
            float inter = fmaxf(iy2 - iy1, 0.f) * fmaxf(ix2 - ix1, 0.f);
            float un = a[j] + ba - inter;                 // >= ba > 0 always
            float iou = inter * __builtin_amdgcn_rcpf(un);
            float w = (iou <= IOU_THR_) ? __expf(-iou * iou) : 0.f;   // -0.5/SIGMA = -1
            s[j] = s[j] * w;                              // self: iou~1 -> w=0 -> 0
            lm = fmaxf(lm, s[j]);
        }
    }
}

// rare fallback for M > 512: wave-local, in-place on global pools. Not expected.
__device__ void nms_glb(int bc, int M, int lane,
        float* __restrict__ ps, float* __restrict__ py1, float* __restrict__ px1,
        float* __restrict__ py2, float* __restrict__ px2, float* __restrict__ pa,
        const int* __restrict__ pidx,
        float* __restrict__ nscore, int* __restrict__ nanchor) {
    int base = bc * CAP_;
    float* S = ps + base; float* Y1 = py1 + base; float* X1 = px1 + base;
    float* Y2 = py2 + base; float* X2 = px2 + base; float* A = pa + base;
    float bvv = -INFINITY; int bii = 0x7FFFFFFF;
    for (int m = lane; m < M; m += 64) { float v = S[m]; if (v > bvv) { bvv = v; bii = m; } }
    #pragma unroll
    for (int off = 32; off > 0; off >>= 1) {
        float ov = __shfl_xor(bvv, off);
        int   oi = __shfl_xor(bii, off);
        if (ov > bvv || (ov == bvv && oi < bii)) { bvv = ov; bii = oi; }
    }
    for (int k = 0; k < MAXK_; k++) {
        float val = bvv;
        if (!(val > SCORE_THR_)) break;
        int bsel = bii;
        if (lane == 0) {
            nscore[bc * MAXK_ + k] = val;
            nanchor[bc * MAXK_ + k] = pidx[base + bsel];
        }
        float by1 = Y1[bsel], bx1 = X1[bsel], by2 = Y2[bsel], bx2 = X2[bsel], ba = A[bsel];
        bvv = -INFINITY; bii = 0x7FFFFFFF;
        for (int m = lane; m < M; m += 64) {
            float s0 = S[m];
            float ns;
            if (s0 == -INFINITY) {
                ns = s0;
            } else {
                float iy1 = fmaxf(Y1[m], by1), ix1 = fmaxf(X1[m], bx1);
                float iy2 = fminf(Y2[m], by2), ix2 = fminf(X2[m], bx2);
                float inter = fmaxf(iy2 - iy1, 0.f) * fmaxf(ix2 - ix1, 0.f);
                float am = A[m];
                float un = am + ba - inter;
                float iou = (am > 0.f && ba > 0.f) ? inter / (un > 0.f ? un : 1.f) : 0.f;
                float w = (iou <= IOU_THR_) ? __expf(-iou * iou) : 0.f;
                ns = (m == bsel) ? -INFINITY : s0 * w;
                S[m] = ns;
            }
            if (ns > bvv) { bvv = ns; bii = m; }
        }
        #pragma unroll
        for (int off = 32; off > 0; off >>= 1) {
            float ov = __shfl_xor(bvv, off);
            int   oi = __shfl_xor(bii, off);
            if (ov > bvv || (ov == bvv && oi < bii)) { bvv = ov; bii = oi; }
        }
    }
}

// ---------------- cooperative mega-kernel: P1 scatter | P2 NMS | P3 rank | P4 masks ----------------
__global__ __launch_bounds__(256, 2) void k_all(
        const float* __restrict__ cls, const float* __restrict__ off4,
        const float* __restrict__ priors, const float* __restrict__ coef,
        const float* __restrict__ proto,
        int* __restrict__ cursors, int* __restrict__ bflags,
        float* __restrict__ ps, float* __restrict__ py1, float* __restrict__ px1,
        float* __restrict__ py2, float* __restrict__ px2, float* __restrict__ pa,
        int* __restrict__ pidx, float* __restrict__ nscore, int* __restrict__ nanchor,
        float* __restrict__ selc, float* __restrict__ out) {
    cg::grid_group grid = cg::this_grid();
    const int tid = threadIdx.x;
    const int bid = blockIdx.x;
    const int lane = tid & 63;
    const int nb = gridDim.x;   // GRID_ = 256

    // ---------- P1: softmax + box decode + pool scatter (1 wave per anchor) ----------
    for (int wid = bid * 4 + (tid >> 6); wid < B_ * N_; wid += nb * 4) {
        int b = wid / N_;
        int n = wid - b * N_;
        const float* x = cls + (size_t)wid * NCLSP1_;
        float v1 = x[lane];                                    // classes 0..63
        float v2 = (lane <= 16) ? x[lane + 64] : -INFINITY;    // classes 64..80
        float mx = wave_max_f32(fmaxf(v1, v2));
        float e1 = __expf(v1 - mx);
        float e2 = (lane <= 16) ? __expf(v2 - mx) : 0.f;
        float sum = wave_sum_f32(e1 + e2);
        float p1 = e1 / sum;
        float p2 = e2 / sum;
        bool q1 = (lane >= 1) && (p1 > SCORE_THR_);            // class 1..63 -> c-1 = lane-1
        bool q2 = (lane <= 16) && (p2 > SCORE_THR_);           // class 64..80 -> c-1 = lane+63
        if (q1 | q2) {
            float4 o  = *(const float4*)(off4 + (size_t)wid * 4);
            float4 pr = *(const float4*)(priors + (size_t)n * 4);
            float d0 = o.x + pr.x, d1 = o.y + pr.y, d2 = o.z + pr.z, d3 = o.w + pr.w;
            float y1 = fminf(d0, d2), y2 = fmaxf(d0, d2);
            float x1 = fminf(d1, d3), x2 = fmaxf(d1, d3);
            float ar = (y2 - y1) * (x2 - x1);
            if (q1) {
                int bc = b * NCLS_ + (lane - 1);
                int pos = atomicAdd(&cursors[bc * 16], 1);
                if (pos < CAP_) {
                    int o0 = bc * CAP_ + pos;
                    ps[o0] = p1; py1[o0] = y1; px1[o0] = x1;
                    py2[o0] = y2; px2[o0] = x2; pa[o0] = ar; pidx[o0] = n;
                }
            }
            if (q2) {
                int bc = b * NCLS_ + (lane + 63);
                int pos = atomicAdd(&cursors[bc * 16], 1);
                if (pos < CAP_) {
                    int o0 = bc * CAP_ + pos;
                    ps[o0] = p2; py1[o0] = y1; px1[o0] = x1;
                    py2[o0] = y2; px2[o0] = x2; pa[o0] = ar; pidx[o0] = n;
                }
            }
        }
    }
    grid.sync();

    // ---------- P2: zero head/selc (all blocks) + per-class NMS (wave 0 of blocks <160) ----------
    for (int i = bid * 256 + tid; i < OUT_HEAD + B_ * MAXOUT_ * MD_; i += nb * 256) {
        if (i < OUT_HEAD) out[i] = 0.f; else selc[i - OUT_HEAD] = 0.f;
    }
    if (bid < NBC_ && (tid >> 6) == 0) {
        int bc = bid;
        int M = cursors[bc * 16];
        if (M > CAP_) M = CAP_;
        for (int k = lane; k < MAXK_; k += 64) { nscore[bc * MAXK_ + k] = 0.f; nanchor[bc * MAXK_ + k] = 0; }
        if (M > 0) {
            if (lane == 0) bflags[bc / NCLS_] = 1;   // pool nonempty <=> some prob>0.3
            if (M <= 64)       nms_reg<1>(bc, M, lane, ps, py1, px1, py2, px2, pa, pidx, nscore, nanchor);
            else if (M <= 128) nms_reg<2>(bc, M, lane, ps, py1, px1, py2, px2, pa, pidx, nscore, nanchor);
            else if (M <= 192) nms_reg<3>(bc, M, lane, ps, py1, px1, py2, px2, pa, pidx, nscore, nanchor);
            else if (M <= 256) nms_reg<4>(bc, M, lane, ps, py1, px1, py2, px2, pa, pidx, nscore, nanchor);
            else if (M <= 512) nms_reg<8>(bc, M, lane, ps, py1, px1, py2, px2, pa, pidx, nscore, nanchor);
            else               nms_glb(bc, M, lane, ps, py1, px1, py2, px2, pa, pidx, nscore, nanchor);
        }
    }
    grid.sync();

    // ---------- P3: rank-based top-300 (global nscore, on-the-fly keys) + num_det ----------
    for (int gth = bid * 256 + tid; gth < B_ * NCLS_ * MAXK_; gth += nb * 256) {
        if (gth < B_) out[OUT_NDET + gth] = bflags[gth] ? (float)MAXOUT_ : 0.f;
        int b = gth / (NCLS_ * MAXK_);
        int i = gth - b * (NCLS_ * MAXK_);
        const float* nsb = nscore + (size_t)b * (NCLS_ * MAXK_);
        float sv = nsb[i];
        if (sv != 0.f) {   // zero-score slots pre-zeroed; they never affect valid ranks
            unsigned long long mykey = ((unsigned long long)__float_as_uint(sv) << 32)
                                     | (unsigned)(0xFFFFFFFFu - (unsigned)i);
            #define KEYAT(ii) ((((unsigned long long)__float_as_uint(nsb[ii])) << 32) \
                               | (unsigned)(0xFFFFFFFFu - (unsigned)(ii)))
            int rank = 0;
            #pragma unroll
            for (int cgp = 0; cgp < NCLS_; cgp += 8) {
                int lo0=0,lo1=0,lo2=0,lo3=0,lo4=0,lo5=0,lo6=0,lo7=0;
                int hi0=MAXK_,hi1=MAXK_,hi2=MAXK_,hi3=MAXK_,hi4=MAXK_,hi5=MAXK_,hi6=MAXK_,hi7=MAXK_;
                #pragma unroll
                for (int it = 0; it < 7; it++) {
                    #define BSTEP(u, lo, hi) { \
                        int mid = (lo + hi) >> 1; \
                        if (lo < hi) { \
                            unsigned long long v = KEYAT((cgp + u) * MAXK_ + mid); \
                            if (v > mykey) lo = mid + 1; else hi = mid; \
                        } }
                    BSTEP(0, lo0, hi0) BSTEP(1, lo1, hi1) BSTEP(2, lo2, hi2) BSTEP(3, lo3, hi3)
                    BSTEP(4, lo4, hi4) BSTEP(5, lo5, hi5) BSTEP(6, lo6, hi6) BSTEP(7, lo7, hi7)
                    #undef BSTEP
                }
                rank += lo0+lo1+lo2+lo3+lo4+lo5+lo6+lo7;
            }
            #undef KEYAT
            if (rank < MAXOUT_) {
                int c = i / MAXK_;
                int anchor = nanchor[(size_t)b * (NCLS_ * MAXK_) + i];
                out[OUT_SCR + b * MAXOUT_ + rank] = sv;
                out[OUT_CLS + b * MAXOUT_ + rank] = (float)(c + 1);
                size_t gb = (size_t)b * N_ + anchor;
                #pragma unroll
                for (int t = 0; t < 4; t++) {
                    float v = off4[gb * 4 + t] + priors[(size_t)anchor * 4 + t];
                    out[OUT_BOXES + ((size_t)b * MAXOUT_ + rank) * 4 + t] = v;
                }
                #pragma unroll
                for (int d = 0; d < MD_; d++) {
                    selc[((size_t)b * MAXOUT_ + rank) * MD_ + d] = coef[gb * MD_ + d];
                }
            }
        }
    }
    grid.sync();

    // ---------- P4: masks = sigmoid(proto @ coefs^T), grid-stride over 608 tiles ----------
    {
        __shared__ float cf[KCHUNK * MD_];
        for (int tile = bid; tile < NTILE; tile += nb) {
            __syncthreads();   // protect cf reuse across tiles
            int pb = tile % 76;
            int kc = (tile / 76) & 3;
            int b  = tile / 304;
            int k0 = kc * KCHUNK;
            for (int i = tid; i < KCHUNK * MD_; i += 256)
                cf[i] = selc[((size_t)b * MAXOUT_ + k0) * MD_ + i];
            __syncthreads();
            int p = pb * 256 + tid;
            if (p < PHW_) {
                const float4* pp = (const float4*)(proto + ((size_t)b * PHW_ + p) * MD_);
                float4 pr[8];
                #pragma unroll
                for (int i = 0; i < 8; i++) pr[i] = pp[i];
                float* ob = out + OUT_MASKS + ((size_t)b * MAXOUT_ + k0) * PHW_ + p;
                for (int kk = 0; kk < KCHUNK; kk++) {
                    const float4* cv = (const float4*)(cf + kk * MD_);
                    float acc = 0.f;
                    #pragma unroll
                    for (int i = 0; i < 8; i++) {
                        float4 c = cv[i];
                        acc += pr[i].x * c.x + pr[i].y * c.y + pr[i].z * c.z + pr[i].w * c.w;
                    }
                    ob[(size_t)kk * PHW_] = 1.f / (1.f + __expf(-acc));
                }
            }
        }
    }
}

// ---------------- launcher: 2 graph nodes (memset + cooperative kernel) ----------------
extern "C" void kernel_launch(void* const* d_in, const int* in_sizes, int n_in,
                              void* d_out, int out_size, void* d_ws, size_t ws_size,
                              hipStream_t stream) {
    const float* pred_offset = (const float*)d_in[0];
    const float* pred_cls    = (const float*)d_in[1];
    const float* pred_coef   = (const float*)d_in[2];
    const float* priors      = (const float*)d_in[3];
    const float* proto       = (const float*)d_in[4];
    float* out = (float*)d_out;
    float* ws  = (float*)d_ws;
    int*   wsi = (int*)d_ws;

    int*   cursors = wsi + OFF_CURSORS;
    int*   bflags  = wsi + OFF_BFLAG;
    float* ps      = ws  + OFF_PS;
    float* py1     = ws  + OFF_PY1;
    float* px1     = ws  + OFF_PX1;
    float* py2     = ws  + OFF_PY2;
    float* px2     = ws  + OFF_PX2;
    float* pa      = ws  + OFF_PA;
    int*   pidx    = wsi + OFF_PIDX;
    float* nscore  = ws  + OFF_NSCORE;
    int*   nanchor = wsi + OFF_NANCH;
    float* selc    = ws  + OFF_SELC;

    hipMemsetAsync(d_ws, 0, (size_t)OFF_PS * 4, stream);   // cursors + bflags

    void* args[] = {
        (void*)&pred_cls, (void*)&pred_offset, (void*)&priors, (void*)&pred_coef,
        (void*)&proto,
        (void*)&cursors, (void*)&bflags,
        (void*)&ps, (void*)&py1, (void*)&px1, (void*)&py2, (void*)&px2, (void*)&pa,
        (void*)&pidx, (void*)&nscore, (void*)&nanchor,
        (void*)&selc, (void*)&out
    };
    hipLaunchCooperativeKernel((const void*)k_all, dim3(GRID_), dim3(256), args, 0, stream);
}

// Round 14
// 139.694 us; speedup vs baseline: 2.0320x; 2.0320x over previous
//
#include <hip/hip_runtime.h>
#include <cstdint>
#include <cstddef>

// ---------------- problem constants ----------------
#define B_ 2
#define N_ 19248
#define NCLSP1_ 81
#define NCLS_ 80
#define MAXK_ 100
#define MAXOUT_ 300
#define PH_ 138
#define PW_ 138
#define PHW_ (PH_*PW_)      // 19044
#define MD_ 32
#define NBC_ (B_*NCLS_)     // 160
#define CAP_ 768            // per-(b,c) pool capacity (observed max M ~190)
#define SCORE_THR_ 0.3f
#define IOU_THR_ 0.5f

// output layout (flat float32 elements in d_out)
#define OUT_BOXES 0
#define OUT_CLS   2400
#define OUT_SCR   3000
#define OUT_MASKS 3600
#define OUT_NDET  11430000
#define OUT_HEAD  3600                     // boxes+cls+scores elements

// workspace layout (element offsets)
#define OFF_CURSORS 0                      // 160*16 ints (one 64B line per class)
#define POOLSZ      (NBC_*CAP_)            // 122880
#define OFF_PS      2576
#define OFF_PY1     (OFF_PS  + POOLSZ)
#define OFF_PX1     (OFF_PY1 + POOLSZ)
#define OFF_PY2     (OFF_PX1 + POOLSZ)
#define OFF_PX2     (OFF_PY2 + POOLSZ)
#define OFF_PA      (OFF_PX2 + POOLSZ)
#define OFF_PIDX    (OFF_PA  + POOLSZ)
#define OFF_NSCORE  (OFF_PIDX + POOLSZ)    // 160*100
#define OFF_NANCH   (OFF_NSCORE + NBC_*MAXK_)
#define OFF_SELC    (OFF_NANCH + NBC_*MAXK_)

// ---------------- wave-wide reduce via DPP (no DS ops) ----------------
__device__ __forceinline__ float wave_max_f32(float x) {
    int v = __float_as_int(x);
    int t;
    #define DPPMAX(ctrl, rm, bm) \
        t = __builtin_amdgcn_update_dpp(v, v, ctrl, rm, bm, false); \
        v = __float_as_int(fmaxf(__int_as_float(v), __int_as_float(t)));
    DPPMAX(0x111, 0xF, 0xF)   // row_shr:1
    DPPMAX(0x112, 0xF, 0xF)   // row_shr:2
    DPPMAX(0x114, 0xF, 0xE)   // row_shr:4
    DPPMAX(0x118, 0xF, 0xC)   // row_shr:8
    DPPMAX(0x142, 0xA, 0xF)   // row_bcast:15
    DPPMAX(0x143, 0xC, 0xF)   // row_bcast:31 ; lane 63 holds wave max
    #undef DPPMAX
    return __int_as_float(__builtin_amdgcn_readlane(v, 63));
}

__device__ __forceinline__ float wave_sum_f32(float x) {
    int v = __float_as_int(x);
    int t;
    #define DPPSUM(ctrl, rm, bm) \
        t = __builtin_amdgcn_update_dpp(v, v, ctrl, rm, bm, false); \
        v = __float_as_int(__int_as_float(v) + __int_as_float(t));
    DPPSUM(0x111, 0xF, 0xF)
    DPPSUM(0x112, 0xF, 0xF)
    DPPSUM(0x114, 0xF, 0xE)
    DPPSUM(0x118, 0xF, 0xC)
    DPPSUM(0x142, 0xA, 0xF)
    DPPSUM(0x143, 0xC, 0xF)
    #undef DPPSUM
    return __int_as_float(__builtin_amdgcn_readlane(v, 63));
}

__device__ __forceinline__ float readlane_f(float v, int l) {
    return __int_as_float(__builtin_amdgcn_readlane(__float_as_int(v), l));
}

// ---------------- kernel 1: fused softmax + box decode + pool scatter ----------------
__global__ __launch_bounds__(256) void k_fused(const float* __restrict__ cls,
        const float* __restrict__ off4, const float* __restrict__ priors,
        int* __restrict__ cursors,
        float* __restrict__ ps, float* __restrict__ py1, float* __restrict__ px1,
        float* __restrict__ py2, float* __restrict__ px2, float* __restrict__ pa,
        int* __restrict__ pidx) {
    int wid = (blockIdx.x * 256 + threadIdx.x) >> 6;   // anchor = global wave id
    int lane = threadIdx.x & 63;
    if (wid >= B_ * N_) return;
    int b = wid / N_;
    int n = wid - b * N_;
    const float* x = cls + (size_t)wid * NCLSP1_;
    float v1 = x[lane];                                    // classes 0..63
    float v2 = (lane <= 16) ? x[lane + 64] : -INFINITY;    // classes 64..80
    float mx = wave_max_f32(fmaxf(v1, v2));
    float e1 = __expf(v1 - mx);
    float e2 = (lane <= 16) ? __expf(v2 - mx) : 0.f;
    float rs = __builtin_amdgcn_rcpf(wave_sum_f32(e1 + e2));
    float p1 = e1 * rs;
    float p2 = e2 * rs;
    bool q1 = (lane >= 1) && (p1 > SCORE_THR_);            // class 1..63 -> c-1 = lane-1
    bool q2 = (lane <= 16) && (p2 > SCORE_THR_);           // class 64..80 -> c-1 = lane+63
    if (q1 | q2) {
        float4 o  = *(const float4*)(off4 + (size_t)wid * 4);
        float4 pr = *(const float4*)(priors + (size_t)n * 4);
        float d0 = o.x + pr.x, d1 = o.y + pr.y, d2 = o.z + pr.z, d3 = o.w + pr.w;
        float y1 = fminf(d0, d2), y2 = fmaxf(d0, d2);
        float x1 = fminf(d1, d3), x2 = fmaxf(d1, d3);
        float ar = (y2 - y1) * (x2 - x1);
        if (q1) {
            int bc = b * NCLS_ + (lane - 1);
            int pos = atomicAdd(&cursors[bc * 16], 1);
            if (pos < CAP_) {
                int o0 = bc * CAP_ + pos;
                ps[o0] = p1; py1[o0] = y1; px1[o0] = x1;
                py2[o0] = y2; px2[o0] = x2; pa[o0] = ar; pidx[o0] = n;
            }
        }
        if (q2) {
            int bc = b * NCLS_ + (lane + 63);
            int pos = atomicAdd(&cursors[bc * 16], 1);
            if (pos < CAP_) {
                int o0 = bc * CAP_ + pos;
                ps[o0] = p2; py1[o0] = y1; px1[o0] = x1;
                py2[o0] = y2; px2[o0] = x2; pa[o0] = ar; pidx[o0] = n;
            }
        }
    }
}

// ---------------- kernel 2: per-(b,c) soft-NMS — lane-local select, no SGPR chain ----------------
// Self-suppress-by-weight (r11-proven): selected box's iou~1 -> w=0 -> score 0.
// Field broadcast: per-lane lowest-j cndmask select (issues parallel to ballot) then a
// single combined ballot -> lsel -> 5 readlanes. Ties resolved lane-major (measure-zero).
template<int J>
__device__ __forceinline__ void nms_reg(int bc, int M, int lane,
        const float* __restrict__ ps, const float* __restrict__ py1,
        const float* __restrict__ px1, const float* __restrict__ py2,
        const float* __restrict__ px2, const float* __restrict__ pa,
        const int* __restrict__ pidx,
        float* __restrict__ nscore, int* __restrict__ nanchor) {
    int base = bc * CAP_;
    float s[J], y1[J], x1[J], y2[J], x2[J], a[J];
    int pid[J];
    #pragma unroll
    for (int j = 0; j < J; j++) {
        int m = lane + 64 * j;
        bool in = (m < M);
        s[j]  = in ? ps[base + m]  : 0.f;    // scores >= 0; padding 0 never selected
        y1[j] = in ? py1[base + m] : 0.f;
        x1[j] = in ? px1[base + m] : 0.f;
        y2[j] = in ? py2[base + m] : 0.f;
        x2[j] = in ? px2[base + m] : 0.f;
        a[j]  = in ? pa[base + m]  : 0.f;    // zero box: inter=0 -> iou 0 -> w 1
        pid[j] = in ? pidx[base + m] : 0;
    }
    float lm = s[0];
    #pragma unroll
    for (int j = 1; j < J; j++) lm = fmaxf(lm, s[j]);
    for (int k = 0; k < MAXK_; k++) {
        float maxv = wave_max_f32(lm);
        if (!(maxv > SCORE_THR_)) break;      // remaining outputs stay 0 (= invalid)
        bool sel[J];
        bool any = false;
        #pragma unroll
        for (int j = 0; j < J; j++) { sel[j] = (s[j] == maxv); any |= sel[j]; }
        // lane-local lowest-j field select — pure VALU, independent of the ballot
        float ty1 = y1[J-1], tx1 = x1[J-1], ty2 = y2[J-1], tx2 = x2[J-1];
        int tpd = pid[J-1];
        #pragma unroll
        for (int j = J - 2; j >= 0; j--) {
            if (sel[j]) { ty1 = y1[j]; tx1 = x1[j]; ty2 = y2[j]; tx2 = x2[j]; tpd = pid[j]; }
        }
        unsigned long long bq = __ballot(any);
        int lsel = __ffsll((long long)bq) - 1;
        float by1 = readlane_f(ty1, lsel);
        float bx1 = readlane_f(tx1, lsel);
        float by2 = readlane_f(ty2, lsel);
        float bx2 = readlane_f(tx2, lsel);
        int   bpd = __builtin_amdgcn_readlane(tpd, lsel);
        float ba  = (by2 - by1) * (bx2 - bx1);   // bitwise == stored pa (same expression)
        if (lane == 0) {
            nscore[bc * MAXK_ + k] = maxv;
            nanchor[bc * MAXK_ + k] = bpd;
        }
        lm = 0.f;
        #pragma unroll
        for (int j = 0; j < J; j++) {
            float iy1 = fmaxf(y1[j], by1), ix1 = fmaxf(x1[j], bx1);
            float iy2 = fminf(y2[j], by2), ix2 = fminf(x2[j], bx2);
            float inter = fmaxf(iy2 - iy1, 0.f) * fmaxf(ix2 - ix1, 0.f);
            float un = a[j] + ba - inter;                 // >= ba > 0 always
            float iou = inter * __builtin_amdgcn_rcpf(un);
            float w = (iou <= IOU_THR_) ? __expf(-iou * iou) : 0.f;   // -0.5/SIGMA = -1
            s[j] = s[j] * w;                              // self: iou~1 -> w=0 -> 0
            lm = fmaxf(lm, s[j]);
        }
    }
}

// rare fallback for M > 512: wave-local, in-place on global pools. Not expected.
__device__ void nms_glb(int bc, int M, int lane,
        float* __restrict__ ps, float* __restrict__ py1, float* __restrict__ px1,
        float* __restrict__ py2, float* __restrict__ px2, float* __restrict__ pa,
        const int* __restrict__ pidx,
        float* __restrict__ nscore, int* __restrict__ nanchor) {
    int base = bc * CAP_;
    float* S = ps + base; float* Y1 = py1 + base; float* X1 = px1 + base;
    float* Y2 = py2 + base; float* X2 = px2 + base; float* A = pa + base;
    float bvv = -INFINITY; int bii = 0x7FFFFFFF;
    for (int m = lane; m < M; m += 64) { float v = S[m]; if (v > bvv) { bvv = v; bii = m; } }
    #pragma unroll
    for (int off = 32; off > 0; off >>= 1) {
        float ov = __shfl_xor(bvv, off);
        int   oi = __shfl_xor(bii, off);
        if (ov > bvv || (ov == bvv && oi < bii)) { bvv = ov; bii = oi; }
    }
    for (int k = 0; k < MAXK_; k++) {
        float val = bvv;
        if (!(val > SCORE_THR_)) break;
        int bsel = bii;
        if (lane == 0) {
            nscore[bc * MAXK_ + k] = val;
            nanchor[bc * MAXK_ + k] = pidx[base + bsel];
        }
        float by1 = Y1[bsel], bx1 = X1[bsel], by2 = Y2[bsel], bx2 = X2[bsel], ba = A[bsel];
        bvv = -INFINITY; bii = 0x7FFFFFFF;
        for (int m = lane; m < M; m += 64) {
            float s0 = S[m];
            float ns;
            if (s0 == -INFINITY) {
                ns = s0;
            } else {
                float iy1 = fmaxf(Y1[m], by1), ix1 = fmaxf(X1[m], bx1);
                float iy2 = fminf(Y2[m], by2), ix2 = fminf(X2[m], bx2);
                float inter = fmaxf(iy2 - iy1, 0.f) * fmaxf(ix2 - ix1, 0.f);
                float am = A[m];
                float un = am + ba - inter;
                float iou = (am > 0.f && ba > 0.f) ? inter / (un > 0.f ? un : 1.f) : 0.f;
                float w = (iou <= IOU_THR_) ? __expf(-iou * iou) : 0.f;
                ns = (m == bsel) ? -INFINITY : s0 * w;
                S[m] = ns;
            }
            if (ns > bvv) { bvv = ns; bii = m; }
        }
        #pragma unroll
        for (int off = 32; off > 0; off >>= 1) {
            float ov = __shfl_xor(bvv, off);
            int   oi = __shfl_xor(bii, off);
            if (ov > bvv || (ov == bvv && oi < bii)) { bvv = ov; bii = oi; }
        }
    }
}

__global__ __launch_bounds__(64) void k_nms(const int* __restrict__ cursors,
        float* __restrict__ ps, float* __restrict__ py1, float* __restrict__ px1,
        float* __restrict__ py2, float* __restrict__ px2, float* __restrict__ pa,
        const int* __restrict__ pidx,
        float* __restrict__ nscore, int* __restrict__ nanchor,
        float* __restrict__ out_head, float* __restrict__ selc) {
    int bc = blockIdx.x;                     // one wave per class: max CU spread
    int lane = threadIdx.x & 63;
    int M = cursors[bc * 16];
    if (M > CAP_) M = CAP_;
    for (int k = lane; k < MAXK_; k += 64) { nscore[bc * MAXK_ + k] = 0.f; nanchor[bc * MAXK_ + k] = 0; }
    // zero output head (boxes/cls/scores) + selc — replaces two memset graph nodes;
    // stream-ordered before k_rank reads/writes them.
    for (int i = bc * 64 + lane; i < OUT_HEAD + B_ * MAXOUT_ * MD_; i += NBC_ * 64) {
        if (i < OUT_HEAD) out_head[i] = 0.f;
        else selc[i - OUT_HEAD] = 0.f;
    }
    if (M <= 0) return;
    if (M <= 64)  { nms_reg<1>(bc, M, lane, ps, py1, px1, py2, px2, pa, pidx, nscore, nanchor); return; }
    if (M <= 128) { nms_reg<2>(bc, M, lane, ps, py1, px1, py2, px2, pa, pidx, nscore, nanchor); return; }
    if (M <= 192) { nms_reg<3>(bc, M, lane, ps, py1, px1, py2, px2, pa, pidx, nscore, nanchor); return; }
    if (M <= 256) { nms_reg<4>(bc, M, lane, ps, py1, px1, py2, px2, pa, pidx, nscore, nanchor); return; }
    if (M <= 512) { nms_reg<8>(bc, M, lane, ps, py1, px1, py2, px2, pa, pidx, nscore, nanchor); return; }
    nms_glb(bc, M, lane, ps, py1, px1, py2, px2, pa, pidx, nscore, nanchor);
}

// ---------------- kernel 3: rank-based top-300 + num_det ----------------
__global__ __launch_bounds__(1024) void k_rank(const float* __restrict__ nscore,
        const int* __restrict__ nanchor,
        const float* __restrict__ off4, const float* __restrict__ priors,
        const float* __restrict__ coef, float* __restrict__ out, float* __restrict__ selc) {
    int b = blockIdx.y;
    int tid = threadIdx.x;
    __shared__ unsigned long long key[NCLS_ * MAXK_];   // 8000 keys, 64 KB
    __shared__ int anyf;
    if (tid == 0) anyf = 0;
    for (int i = tid; i < NCLS_ * MAXK_; i += 1024) {
        float s = nscore[b * (NCLS_ * MAXK_) + i];
        key[i] = ((unsigned long long)__float_as_uint(s) << 32)
               | (unsigned)(0xFFFFFFFFu - (unsigned)i);
    }
    __syncthreads();
    // num_det: any class selected >=1 box <=> its first slot score > 0
    if (tid < NCLS_ && (unsigned)(key[tid * MAXK_] >> 32) != 0u) anyf = 1;  // benign race
    __syncthreads();
    if (blockIdx.x == 0 && tid == 0) out[OUT_NDET + b] = anyf ? (float)MAXOUT_ : 0.f;

    int i = blockIdx.x * 1000 + tid;
    if (tid >= 1000 || i >= NCLS_ * MAXK_) return;
    unsigned long long mykey = key[i];
    // zero-score candidates: their would-be slots are pre-zeroed by k_nms (exact match
    // to reference padding) and they never affect valid candidates' ranks.
    if ((unsigned)(mykey >> 32) == 0u) return;

    int rank = 0;
    #pragma unroll
    for (int cg = 0; cg < NCLS_; cg += 8) {
        int lo0=0,lo1=0,lo2=0,lo3=0,lo4=0,lo5=0,lo6=0,lo7=0;
        int hi0=MAXK_,hi1=MAXK_,hi2=MAXK_,hi3=MAXK_,hi4=MAXK_,hi5=MAXK_,hi6=MAXK_,hi7=MAXK_;
        #pragma unroll
        for (int it = 0; it < 7; it++) {
            #define BSTEP(u, lo, hi) { \
                int mid = (lo + hi) >> 1; \
                if (lo < hi) { \
                    unsigned long long v = key[(cg + u) * MAXK_ + mid]; \
                    if (v > mykey) lo = mid + 1; else hi = mid; \
                } }
            BSTEP(0, lo0, hi0) BSTEP(1, lo1, hi1) BSTEP(2, lo2, hi2) BSTEP(3, lo3, hi3)
            BSTEP(4, lo4, hi4) BSTEP(5, lo5, hi5) BSTEP(6, lo6, hi6) BSTEP(7, lo7, hi7)
            #undef BSTEP
        }
        rank += lo0+lo1+lo2+lo3+lo4+lo5+lo6+lo7;
    }
    if (rank >= MAXOUT_) return;

    float s = __uint_as_float((unsigned)(mykey >> 32));
    int c = i / MAXK_;
    int anchor = nanchor[b * (NCLS_ * MAXK_) + i];
    out[OUT_SCR + b * MAXOUT_ + rank] = s;
    out[OUT_CLS + b * MAXOUT_ + rank] = (float)(c + 1);
    size_t gb = (size_t)b * N_ + anchor;
    #pragma unroll
    for (int t = 0; t < 4; t++) {
        float v = off4[gb * 4 + t] + priors[(size_t)anchor * 4 + t];
        out[OUT_BOXES + ((size_t)b * MAXOUT_ + rank) * 4 + t] = v;
    }
    #pragma unroll
    for (int d = 0; d < MD_; d++) {
        selc[((size_t)b * MAXOUT_ + rank) * MD_ + d] = coef[gb * MD_ + d];
    }
}

// ---------------- kernel 4: masks = sigmoid(proto @ coefs^T) ----------------
#define KCHUNK 75   // 300/4
__global__ __launch_bounds__(256) void k_masks(const float* __restrict__ proto,
        const float* __restrict__ selc, float* __restrict__ om) {
    int b = blockIdx.z;
    int k0 = blockIdx.y * KCHUNK;
    int p = blockIdx.x * 256 + threadIdx.x;
    __shared__ float cf[KCHUNK * MD_];
    for (int i = threadIdx.x; i < KCHUNK * MD_; i += 256)
        cf[i] = selc[((size_t)b * MAXOUT_ + k0) * MD_ + i];
    __syncthreads();
    if (p >= PHW_) return;
    const float4* pp = (const float4*)(proto + ((size_t)b * PHW_ + p) * MD_);
    float4 pr[8];
    #pragma unroll
    for (int i = 0; i < 8; i++) pr[i] = pp[i];
    float* ob = om + ((size_t)b * MAXOUT_ + k0) * PHW_ + p;
    for (int kk = 0; kk < KCHUNK; kk++) {
        const float4* cv = (const float4*)(cf + kk * MD_);
        float acc = 0.f;
        #pragma unroll
        for (int i = 0; i < 8; i++) {
            float4 c = cv[i];
            acc += pr[i].x * c.x + pr[i].y * c.y + pr[i].z * c.z + pr[i].w * c.w;
        }
        ob[(size_t)kk * PHW_] = __builtin_amdgcn_rcpf(1.f + __expf(-acc));
    }
}

// ---------------- launcher: 5 graph nodes ----------------
extern "C" void kernel_launch(void* const* d_in, const int* in_sizes, int n_in,
                              void* d_out, int out_size, void* d_ws, size_t ws_size,
                              hipStream_t stream) {
    const float* pred_offset = (const float*)d_in[0];
    const float* pred_cls    = (const float*)d_in[1];
    const float* pred_coef   = (const float*)d_in[2];
    const float* priors      = (const float*)d_in[3];
    const float* proto       = (const float*)d_in[4];
    float* out = (float*)d_out;
    float* ws  = (float*)d_ws;
    int*   wsi = (int*)d_ws;

    int*   cursors = wsi + OFF_CURSORS;
    float* ps      = ws  + OFF_PS;
    float* py1     = ws  + OFF_PY1;
    float* px1     = ws  + OFF_PX1;
    float* py2     = ws  + OFF_PY2;
    float* px2     = ws  + OFF_PX2;
    float* pa      = ws  + OFF_PA;
    int*   pidx    = wsi + OFF_PIDX;
    float* nscore  = ws  + OFF_NSCORE;
    int*   nanchor = wsi + OFF_NANCH;
    float* selc    = ws  + OFF_SELC;

    hipMemsetAsync(d_ws, 0, 2560 * 4, stream);   // cursors (first-call state unknown)

    k_fused<<<(B_ * N_ * 64 + 255) / 256, 256, 0, stream>>>(pred_cls, pred_offset, priors,
            cursors, ps, py1, px1, py2, px2, pa, pidx);
    k_nms<<<NBC_, 64, 0, stream>>>(cursors, ps, py1, px1, py2, px2, pa, pidx,
                                   nscore, nanchor, out, selc);
    k_rank<<<dim3(8, B_), 1024, 0, stream>>>(nscore, nanchor,
                                             pred_offset, priors, pred_coef, out, selc);
    k_masks<<<dim3((PHW_ + 255) / 256, MAXOUT_ / KCHUNK, B_), 256, 0, stream>>>(proto, selc, out + OUT_MASKS);
}

// Round 15
// 135.055 us; speedup vs baseline: 2.1018x; 1.0343x over previous
//
#include <hip/hip_runtime.h>
#include <cstdint>
#include <cstddef>

// ---------------- problem constants ----------------
#define B_ 2
#define N_ 19248
#define NCLSP1_ 81
#define NCLS_ 80
#define MAXK_ 100
#define MAXOUT_ 300
#define PH_ 138
#define PW_ 138
#define PHW_ (PH_*PW_)      // 19044
#define MD_ 32
#define NBC_ (B_*NCLS_)     // 160
#define CAP_ 768            // per-(b,c) pool capacity (observed max M ~190)
#define SCORE_THR_ 0.3f
#define IOU_THR_ 0.5f

// output layout (flat float32 elements in d_out)
#define OUT_BOXES 0
#define OUT_CLS   2400
#define OUT_SCR   3000
#define OUT_MASKS 3600
#define OUT_NDET  11430000
#define OUT_HEAD  3600                     // boxes+cls+scores elements

// workspace layout (element offsets)
#define OFF_CURSORS 0                      // 160*16 ints (one 64B line per class)
#define POOLSZ      (NBC_*CAP_)            // 122880
#define OFF_PS      2576
#define OFF_PY1     (OFF_PS  + POOLSZ)
#define OFF_PX1     (OFF_PY1 + POOLSZ)
#define OFF_PY2     (OFF_PX1 + POOLSZ)
#define OFF_PX2     (OFF_PY2 + POOLSZ)
#define OFF_PA      (OFF_PX2 + POOLSZ)
#define OFF_PIDX    (OFF_PA  + POOLSZ)
#define OFF_NSCORE  (OFF_PIDX + POOLSZ)    // 160*100
#define OFF_NANCH   (OFF_NSCORE + NBC_*MAXK_)
#define OFF_SELC    (OFF_NANCH + NBC_*MAXK_)

// ---------------- wave-wide reduce via DPP (no DS ops) ----------------
__device__ __forceinline__ float wave_max_f32(float x) {
    int v = __float_as_int(x);
    int t;
    #define DPPMAX(ctrl, rm, bm) \
        t = __builtin_amdgcn_update_dpp(v, v, ctrl, rm, bm, false); \
        v = __float_as_int(fmaxf(__int_as_float(v), __int_as_float(t)));
    DPPMAX(0x111, 0xF, 0xF)   // row_shr:1
    DPPMAX(0x112, 0xF, 0xF)   // row_shr:2
    DPPMAX(0x114, 0xF, 0xE)   // row_shr:4
    DPPMAX(0x118, 0xF, 0xC)   // row_shr:8
    DPPMAX(0x142, 0xA, 0xF)   // row_bcast:15
    DPPMAX(0x143, 0xC, 0xF)   // row_bcast:31 ; lane 63 holds wave max
    #undef DPPMAX
    return __int_as_float(__builtin_amdgcn_readlane(v, 63));
}

__device__ __forceinline__ float wave_sum_f32(float x) {
    int v = __float_as_int(x);
    int t;
    #define DPPSUM(ctrl, rm, bm) \
        t = __builtin_amdgcn_update_dpp(v, v, ctrl, rm, bm, false); \
        v = __float_as_int(__int_as_float(v) + __int_as_float(t));
    DPPSUM(0x111, 0xF, 0xF)
    DPPSUM(0x112, 0xF, 0xF)
    DPPSUM(0x114, 0xF, 0xE)
    DPPSUM(0x118, 0xF, 0xC)
    DPPSUM(0x142, 0xA, 0xF)
    DPPSUM(0x143, 0xC, 0xF)
    #undef DPPSUM
    return __int_as_float(__builtin_amdgcn_readlane(v, 63));
}

__device__ __forceinline__ float readlane_f(float v, int l) {
    return __int_as_float(__builtin_amdgcn_readlane(__float_as_int(v), l));
}

// ---------------- kernel 1: fused softmax + box decode + pool scatter ----------------
__global__ __launch_bounds__(256) void k_fused(const float* __restrict__ cls,
        const float* __restrict__ off4, const float* __restrict__ priors,
        int* __restrict__ cursors,
        float* __restrict__ ps, float* __restrict__ py1, float* __restrict__ px1,
        float* __restrict__ py2, float* __restrict__ px2, float* __restrict__ pa,
        int* __restrict__ pidx) {
    int wid = (blockIdx.x * 256 + threadIdx.x) >> 6;   // anchor = global wave id
    int lane = threadIdx.x & 63;
    if (wid >= B_ * N_) return;
    int b = wid / N_;
    int n = wid - b * N_;
    const float* x = cls + (size_t)wid * NCLSP1_;
    float v1 = x[lane];                                    // classes 0..63
    float v2 = (lane <= 16) ? x[lane + 64] : -INFINITY;    // classes 64..80
    float mx = wave_max_f32(fmaxf(v1, v2));
    float e1 = __expf(v1 - mx);
    float e2 = (lane <= 16) ? __expf(v2 - mx) : 0.f;
    float rs = __builtin_amdgcn_rcpf(wave_sum_f32(e1 + e2));
    float p1 = e1 * rs;
    float p2 = e2 * rs;
    bool q1 = (lane >= 1) && (p1 > SCORE_THR_);            // class 1..63 -> c-1 = lane-1
    bool q2 = (lane <= 16) && (p2 > SCORE_THR_);           // class 64..80 -> c-1 = lane+63
    if (q1 | q2) {
        float4 o  = *(const float4*)(off4 + (size_t)wid * 4);
        float4 pr = *(const float4*)(priors + (size_t)n * 4);
        float d0 = o.x + pr.x, d1 = o.y + pr.y, d2 = o.z + pr.z, d3 = o.w + pr.w;
        float y1 = fminf(d0, d2), y2 = fmaxf(d0, d2);
        float x1 = fminf(d1, d3), x2 = fmaxf(d1, d3);
        float ar = (y2 - y1) * (x2 - x1);
        if (q1) {
            int bc = b * NCLS_ + (lane - 1);
            int pos = atomicAdd(&cursors[bc * 16], 1);
            if (pos < CAP_) {
                int o0 = bc * CAP_ + pos;
                ps[o0] = p1; py1[o0] = y1; px1[o0] = x1;
                py2[o0] = y2; px2[o0] = x2; pa[o0] = ar; pidx[o0] = n;
            }
        }
        if (q2) {
            int bc = b * NCLS_ + (lane + 63);
            int pos = atomicAdd(&cursors[bc * 16], 1);
            if (pos < CAP_) {
                int o0 = bc * CAP_ + pos;
                ps[o0] = p2; py1[o0] = y1; px1[o0] = x1;
                py2[o0] = y2; px2[o0] = x2; pa[o0] = ar; pidx[o0] = n;
            }
        }
    }
}

// ---------------- kernel 2: per-(b,c) soft-NMS — lane-local select, no SGPR chain ----------------
template<int J>
__device__ __forceinline__ void nms_reg(int bc, int M, int lane,
        const float* __restrict__ ps, const float* __restrict__ py1,
        const float* __restrict__ px1, const float* __restrict__ py2,
        const float* __restrict__ px2, const float* __restrict__ pa,
        const int* __restrict__ pidx,
        float* __restrict__ nscore, int* __restrict__ nanchor) {
    int base = bc * CAP_;
    float s[J], y1[J], x1[J], y2[J], x2[J], a[J];
    int pid[J];
    #pragma unroll
    for (int j = 0; j < J; j++) {
        int m = lane + 64 * j;
        bool in = (m < M);
        s[j]  = in ? ps[base + m]  : 0.f;    // scores >= 0; padding 0 never selected
        y1[j] = in ? py1[base + m] : 0.f;
        x1[j] = in ? px1[base + m] : 0.f;
        y2[j] = in ? py2[base + m] : 0.f;
        x2[j] = in ? px2[base + m] : 0.f;
        a[j]  = in ? pa[base + m]  : 0.f;    // zero box: inter=0 -> iou 0 -> w 1
        pid[j] = in ? pidx[base + m] : 0;
    }
    float lm = s[0];
    #pragma unroll
    for (int j = 1; j < J; j++) lm = fmaxf(lm, s[j]);
    for (int k = 0; k < MAXK_; k++) {
        float maxv = wave_max_f32(lm);
        if (!(maxv > SCORE_THR_)) break;      // remaining outputs stay 0 (= invalid)
        bool sel[J];
        bool any = false;
        #pragma unroll
        for (int j = 0; j < J; j++) { sel[j] = (s[j] == maxv); any |= sel[j]; }
        // lane-local lowest-j field select — pure VALU, independent of the ballot
        float ty1 = y1[J-1], tx1 = x1[J-1], ty2 = y2[J-1], tx2 = x2[J-1];
        int tpd = pid[J-1];
        #pragma unroll
        for (int j = J - 2; j >= 0; j--) {
            if (sel[j]) { ty1 = y1[j]; tx1 = x1[j]; ty2 = y2[j]; tx2 = x2[j]; tpd = pid[j]; }
        }
        unsigned long long bq = __ballot(any);
        int lsel = __ffsll((long long)bq) - 1;
        float by1 = readlane_f(ty1, lsel);
        float bx1 = readlane_f(tx1, lsel);
        float by2 = readlane_f(ty2, lsel);
        float bx2 = readlane_f(tx2, lsel);
        int   bpd = __builtin_amdgcn_readlane(tpd, lsel);
        float ba  = (by2 - by1) * (bx2 - bx1);   // bitwise == stored pa (same expression)
        if (lane == 0) {
            nscore[bc * MAXK_ + k] = maxv;
            nanchor[bc * MAXK_ + k] = bpd;
        }
        lm = 0.f;
        #pragma unroll
        for (int j = 0; j < J; j++) {
            float iy1 = fmaxf(y1[j], by1), ix1 = fmaxf(x1[j], bx1);
            float iy2 = fminf(y2[j], by2), ix2 = fminf(x2[j], bx2);
            float inter = fmaxf(iy2 - iy1, 0.f) * fmaxf(ix2 - ix1, 0.f);
            float un = a[j] + ba - inter;                 // >= ba > 0 always
            float iou = inter * __builtin_amdgcn_rcpf(un);
            float w = (iou <= IOU_THR_) ? __expf(-iou * iou) : 0.f;   // -0.5/SIGMA = -1
            s[j] = s[j] * w;                              // self: iou~1 -> w=0 -> 0
            lm = fmaxf(lm, s[j]);
        }
    }
}

// rare fallback for M > 512: wave-local, in-place on global pools. Not expected.
__device__ void nms_glb(int bc, int M, int lane,
        float* __restrict__ ps, float* __restrict__ py1, float* __restrict__ px1,
        float* __restrict__ py2, float* __restrict__ px2, float* __restrict__ pa,
        const int* __restrict__ pidx,
        float* __restrict__ nscore, int* __restrict__ nanchor) {
    int base = bc * CAP_;
    float* S = ps + base; float* Y1 = py1 + base; float* X1 = px1 + base;
    float* Y2 = py2 + base; float* X2 = px2 + base; float* A = pa + base;
    float bvv = -INFINITY; int bii = 0x7FFFFFFF;
    for (int m = lane; m < M; m += 64) { float v = S[m]; if (v > bvv) { bvv = v; bii = m; } }
    #pragma unroll
    for (int off = 32; off > 0; off >>= 1) {
        float ov = __shfl_xor(bvv, off);
        int   oi = __shfl_xor(bii, off);
        if (ov > bvv || (ov == bvv && oi < bii)) { bvv = ov; bii = oi; }
    }
    for (int k = 0; k < MAXK_; k++) {
        float val = bvv;
        if (!(val > SCORE_THR_)) break;
        int bsel = bii;
        if (lane == 0) {
            nscore[bc * MAXK_ + k] = val;
            nanchor[bc * MAXK_ + k] = pidx[base + bsel];
        }
        float by1 = Y1[bsel], bx1 = X1[bsel], by2 = Y2[bsel], bx2 = X2[bsel], ba = A[bsel];
        bvv = -INFINITY; bii = 0x7FFFFFFF;
        for (int m = lane; m < M; m += 64) {
            float s0 = S[m];
            float ns;
            if (s0 == -INFINITY) {
                ns = s0;
            } else {
                float iy1 = fmaxf(Y1[m], by1), ix1 = fmaxf(X1[m], bx1);
                float iy2 = fminf(Y2[m], by2), ix2 = fminf(X2[m], bx2);
                float inter = fmaxf(iy2 - iy1, 0.f) * fmaxf(ix2 - ix1, 0.f);
                float am = A[m];
                float un = am + ba - inter;
                float iou = (am > 0.f && ba > 0.f) ? inter / (un > 0.f ? un : 1.f) : 0.f;
                float w = (iou <= IOU_THR_) ? __expf(-iou * iou) : 0.f;
                ns = (m == bsel) ? -INFINITY : s0 * w;
                S[m] = ns;
            }
            if (ns > bvv) { bvv = ns; bii = m; }
        }
        #pragma unroll
        for (int off = 32; off > 0; off >>= 1) {
            float ov = __shfl_xor(bvv, off);
            int   oi = __shfl_xor(bii, off);
            if (ov > bvv || (ov == bvv && oi < bii)) { bvv = ov; bii = oi; }
        }
    }
}

__global__ __launch_bounds__(64) void k_nms(const int* __restrict__ cursors,
        float* __restrict__ ps, float* __restrict__ py1, float* __restrict__ px1,
        float* __restrict__ py2, float* __restrict__ px2, float* __restrict__ pa,
        const int* __restrict__ pidx,
        float* __restrict__ nscore, int* __restrict__ nanchor,
        float* __restrict__ out_head, float* __restrict__ selc) {
    int bc = blockIdx.x;                     // one wave per class: max CU spread
    int lane = threadIdx.x & 63;
    int M = cursors[bc * 16];
    if (M > CAP_) M = CAP_;
    for (int k = lane; k < MAXK_; k += 64) { nscore[bc * MAXK_ + k] = 0.f; nanchor[bc * MAXK_ + k] = 0; }
    // zero output head (boxes/cls/scores) + selc — replaces two memset graph nodes;
    // stream-ordered before k_rank reads/writes them.
    for (int i = bc * 64 + lane; i < OUT_HEAD + B_ * MAXOUT_ * MD_; i += NBC_ * 64) {
        if (i < OUT_HEAD) out_head[i] = 0.f;
        else selc[i - OUT_HEAD] = 0.f;
    }
    if (M <= 0) return;
    if (M <= 64)  { nms_reg<1>(bc, M, lane, ps, py1, px1, py2, px2, pa, pidx, nscore, nanchor); return; }
    if (M <= 128) { nms_reg<2>(bc, M, lane, ps, py1, px1, py2, px2, pa, pidx, nscore, nanchor); return; }
    if (M <= 192) { nms_reg<3>(bc, M, lane, ps, py1, px1, py2, px2, pa, pidx, nscore, nanchor); return; }
    if (M <= 256) { nms_reg<4>(bc, M, lane, ps, py1, px1, py2, px2, pa, pidx, nscore, nanchor); return; }
    if (M <= 512) { nms_reg<8>(bc, M, lane, ps, py1, px1, py2, px2, pa, pidx, nscore, nanchor); return; }
    nms_glb(bc, M, lane, ps, py1, px1, py2, px2, pa, pidx, nscore, nanchor);
}

// ---------------- kernel 3: rank-based top-300 + num_det ----------------
__global__ __launch_bounds__(1024) void k_rank(const float* __restrict__ nscore,
        const int* __restrict__ nanchor,
        const float* __restrict__ off4, const float* __restrict__ priors,
        const float* __restrict__ coef, float* __restrict__ out, float* __restrict__ selc) {
    int b = blockIdx.y;
    int tid = threadIdx.x;
    __shared__ unsigned long long key[NCLS_ * MAXK_];   // 8000 keys, 64 KB
    __shared__ int anyf;
    if (tid == 0) anyf = 0;
    for (int i = tid; i < NCLS_ * MAXK_; i += 1024) {
        float s = nscore[b * (NCLS_ * MAXK_) + i];
        key[i] = ((unsigned long long)__float_as_uint(s) << 32)
               | (unsigned)(0xFFFFFFFFu - (unsigned)i);
    }
    __syncthreads();
    // num_det: any class selected >=1 box <=> its first slot score > 0
    if (tid < NCLS_ && (unsigned)(key[tid * MAXK_] >> 32) != 0u) anyf = 1;  // benign race
    __syncthreads();
    if (blockIdx.x == 0 && tid == 0) out[OUT_NDET + b] = anyf ? (float)MAXOUT_ : 0.f;

    int i = blockIdx.x * 1000 + tid;
    if (tid >= 1000 || i >= NCLS_ * MAXK_) return;
    unsigned long long mykey = key[i];
    if ((unsigned)(mykey >> 32) == 0u) return;

    int rank = 0;
    #pragma unroll
    for (int cg = 0; cg < NCLS_; cg += 8) {
        int lo0=0,lo1=0,lo2=0,lo3=0,lo4=0,lo5=0,lo6=0,lo7=0;
        int hi0=MAXK_,hi1=MAXK_,hi2=MAXK_,hi3=MAXK_,hi4=MAXK_,hi5=MAXK_,hi6=MAXK_,hi7=MAXK_;
        #pragma unroll
        for (int it = 0; it < 7; it++) {
            #define BSTEP(u, lo, hi) { \
                int mid = (lo + hi) >> 1; \
                if (lo < hi) { \
                    unsigned long long v = key[(cg + u) * MAXK_ + mid]; \
                    if (v > mykey) lo = mid + 1; else hi = mid; \
                } }
            BSTEP(0, lo0, hi0) BSTEP(1, lo1, hi1) BSTEP(2, lo2, hi2) BSTEP(3, lo3, hi3)
            BSTEP(4, lo4, hi4) BSTEP(5, lo5, hi5) BSTEP(6, lo6, hi6) BSTEP(7, lo7, hi7)
            #undef BSTEP
        }
        rank += lo0+lo1+lo2+lo3+lo4+lo5+lo6+lo7;
    }
    if (rank >= MAXOUT_) return;

    float s = __uint_as_float((unsigned)(mykey >> 32));
    int c = i / MAXK_;
    int anchor = nanchor[b * (NCLS_ * MAXK_) + i];
    out[OUT_SCR + b * MAXOUT_ + rank] = s;
    out[OUT_CLS + b * MAXOUT_ + rank] = (float)(c + 1);
    size_t gb = (size_t)b * N_ + anchor;
    #pragma unroll
    for (int t = 0; t < 4; t++) {
        float v = off4[gb * 4 + t] + priors[(size_t)anchor * 4 + t];
        out[OUT_BOXES + ((size_t)b * MAXOUT_ + rank) * 4 + t] = v;
    }
    #pragma unroll
    for (int d = 0; d < MD_; d++) {
        selc[((size_t)b * MAXOUT_ + rank) * MD_ + d] = coef[gb * MD_ + d];
    }
}

// ---------------- kernel 4: masks — 2 pixels/thread, register-staged coefs ----------------
// Raises FMA:LDS ratio from 8 to 16 per ds_read_b128 and halves store instructions
// (float2). LDS instruction traffic per output drops 2x; block count halves.
#define KCHUNK 75   // 300/4
__global__ __launch_bounds__(256) void k_masks(const float* __restrict__ proto,
        const float* __restrict__ selc, float* __restrict__ om) {
    int b = blockIdx.z;
    int k0 = blockIdx.y * KCHUNK;
    int p0 = blockIdx.x * 512 + threadIdx.x * 2;   // two adjacent pixels per thread
    __shared__ float cf[KCHUNK * MD_];
    for (int i = threadIdx.x; i < KCHUNK * MD_; i += 256)
        cf[i] = selc[((size_t)b * MAXOUT_ + k0) * MD_ + i];
    __syncthreads();
    if (p0 >= PHW_) return;                        // PHW even -> p0<PHW implies p0+1<PHW
    const float4* pp0 = (const float4*)(proto + ((size_t)b * PHW_ + p0) * MD_);
    const float4* pp1 = (const float4*)(proto + ((size_t)b * PHW_ + p0 + 1) * MD_);
    float4 pr0[8], pr1[8];
    #pragma unroll
    for (int i = 0; i < 8; i++) { pr0[i] = pp0[i]; pr1[i] = pp1[i]; }
    float* ob = om + ((size_t)b * MAXOUT_ + k0) * PHW_ + p0;
    for (int kk = 0; kk < KCHUNK; kk++) {
        float4 cv[8];
        const float4* cvp = (const float4*)(cf + kk * MD_);
        #pragma unroll
        for (int i = 0; i < 8; i++) cv[i] = cvp[i];
        float acc0 = 0.f, acc1 = 0.f;
        #pragma unroll
        for (int i = 0; i < 8; i++) {
            float4 c = cv[i];
            acc0 += pr0[i].x * c.x + pr0[i].y * c.y + pr0[i].z * c.z + pr0[i].w * c.w;
            acc1 += pr1[i].x * c.x + pr1[i].y * c.y + pr1[i].z * c.z + pr1[i].w * c.w;
        }
        float2 r;
        r.x = __builtin_amdgcn_rcpf(1.f + __expf(-acc0));
        r.y = __builtin_amdgcn_rcpf(1.f + __expf(-acc1));
        *(float2*)(ob + (size_t)kk * PHW_) = r;
    }
}

// ---------------- launcher: 5 graph nodes ----------------
extern "C" void kernel_launch(void* const* d_in, const int* in_sizes, int n_in,
                              void* d_out, int out_size, void* d_ws, size_t ws_size,
                              hipStream_t stream) {
    const float* pred_offset = (const float*)d_in[0];
    const float* pred_cls    = (const float*)d_in[1];
    const float* pred_coef   = (const float*)d_in[2];
    const float* priors      = (const float*)d_in[3];
    const float* proto       = (const float*)d_in[4];
    float* out = (float*)d_out;
    float* ws  = (float*)d_ws;
    int*   wsi = (int*)d_ws;

    int*   cursors = wsi + OFF_CURSORS;
    float* ps      = ws  + OFF_PS;
    float* py1     = ws  + OFF_PY1;
    float* px1     = ws  + OFF_PX1;
    float* py2     = ws  + OFF_PY2;
    float* px2     = ws  + OFF_PX2;
    float* pa      = ws  + OFF_PA;
    int*   pidx    = wsi + OFF_PIDX;
    float* nscore  = ws  + OFF_NSCORE;
    int*   nanchor = wsi + OFF_NANCH;
    float* selc    = ws  + OFF_SELC;

    hipMemsetAsync(d_ws, 0, 2560 * 4, stream);   // cursors (first-call state unknown)

    k_fused<<<(B_ * N_ * 64 + 255) / 256, 256, 0, stream>>>(pred_cls, pred_offset, priors,
            cursors, ps, py1, px1, py2, px2, pa, pidx);
    k_nms<<<NBC_, 64, 0, stream>>>(cursors, ps, py1, px1, py2, px2, pa, pidx,
                                   nscore, nanchor, out, selc);
    k_rank<<<dim3(8, B_), 1024, 0, stream>>>(nscore, nanchor,
                                             pred_offset, priors, pred_coef, out, selc);
    k_masks<<<dim3((PHW_ + 511) / 512, MAXOUT_ / KCHUNK, B_), 256, 0, stream>>>(proto, selc, out + OUT_MASKS);
}